// Round 1
// baseline (1631.111 us; speedup 1.0000x reference)
//
#include <hip/hip_runtime.h>
#include <hip/hip_bf16.h>

#define DEV_INLINE __device__ __forceinline__

constexpr int NLAYERS = 2;
constexpr int DM = 512;     // d_model
constexpr int NH = 8;       // heads
constexpr int DHD = 64;     // head dim
constexpr int FF = 2048;    // dff
constexpr int TD = 8;       // time dim
constexpr int BB = 8;       // batch
constexpr int LL = 512;     // seq len
constexpr int ROWS = BB * LL;  // 4096

constexpr float TWO_PI_F = 6.28318530717958647692f;
constexpr float INV_E8 = 3.3546262790251185e-4f;  // exp(-sqrt(64))^-1 = e^-8

// ---------------------------------------------------------------------------
// Small FFNs on t: computes tp = 2*pi*pv*t, sg = ffn_s + 1e-6, be = ffn_b
// One thread per (b,l). 4096 threads.
// ---------------------------------------------------------------------------
DEV_INLINE void ffn2_small(float tv,
                           const float* __restrict__ w1, const float* __restrict__ b1,
                           const float* __restrict__ w2, const float* __restrict__ b2,
                           float* out) {
  float h[TD];
#pragma unroll
  for (int d = 0; d < TD; ++d) h[d] = fmaxf(tv * w1[d] + b1[d], 0.f);
#pragma unroll
  for (int j = 0; j < TD; ++j) {
    float acc = b2[j];
#pragma unroll
    for (int d = 0; d < TD; ++d) acc += h[d] * w2[d * TD + j];
    out[j] = fmaxf(acc, 0.f);
  }
}

__global__ __launch_bounds__(256) void small_ffn_kernel(
    const float* __restrict__ t,
    const float* __restrict__ pw1, const float* __restrict__ pb1,
    const float* __restrict__ pw2, const float* __restrict__ pb2,
    const float* __restrict__ sw1, const float* __restrict__ sb1,
    const float* __restrict__ sw2, const float* __restrict__ sb2,
    const float* __restrict__ bw1, const float* __restrict__ bb1,
    const float* __restrict__ bw2, const float* __restrict__ bb2,
    float* __restrict__ tp, float* __restrict__ sg, float* __restrict__ be) {
  const int i = blockIdx.x * 256 + threadIdx.x;  // b*LL + l
  if (i >= ROWS) return;
  const float tv = t[i];
  float o[TD];
  ffn2_small(tv, pw1, pb1, pw2, pb2, o);
#pragma unroll
  for (int d = 0; d < TD; ++d) tp[(size_t)i * TD + d] = TWO_PI_F * o[d] * tv;
  ffn2_small(tv, sw1, sb1, sw2, sb2, o);
#pragma unroll
  for (int d = 0; d < TD; ++d) sg[(size_t)i * TD + d] = o[d] + 1e-6f;
  ffn2_small(tv, bw1, bb1, bw2, bb2, o);
#pragma unroll
  for (int d = 0; d < TD; ++d) be[(size_t)i * TD + d] = o[d];
}

// ---------------------------------------------------------------------------
// kern kernel: kernS[b,q,k] = e^-8 * sum_d be_q*be_k*local*expenc*cosenc
// grid (LL/256, LL, BB), 256 threads over k
// ---------------------------------------------------------------------------
DEV_INLINE void load8(const float* __restrict__ p, float* o) {
  float4 a = *reinterpret_cast<const float4*>(p);
  float4 b = *reinterpret_cast<const float4*>(p + 4);
  o[0] = a.x; o[1] = a.y; o[2] = a.z; o[3] = a.w;
  o[4] = b.x; o[5] = b.y; o[6] = b.z; o[7] = b.w;
}

__global__ __launch_bounds__(256) void kern_kernel(
    const float* __restrict__ t, const float* __restrict__ tp,
    const float* __restrict__ sg, const float* __restrict__ be,
    float* __restrict__ kernS) {
  const int k = blockIdx.x * 256 + threadIdx.x;
  const int q = blockIdx.y;
  const int b = blockIdx.z;
  const size_t iq = (size_t)b * LL + q;
  const size_t ik = (size_t)b * LL + k;
  const float tq = t[iq], tk = t[ik];
  const float diff = tq - tk;
  const float d2 = diff * diff;

  float tpq[TD], sgq[TD], beq[TD], tpk[TD], sgk[TD], bek[TD];
  load8(tp + iq * TD, tpq);
  load8(sg + iq * TD, sgq);
  load8(be + iq * TD, beq);
  load8(tp + ik * TD, tpk);
  load8(sg + ik * TD, sgk);
  load8(be + ik * TD, bek);

  float acc = 0.f;
#pragma unroll
  for (int d = 0; d < TD; ++d) {
    const float sq = sgq[d], sk = sgk[d];
    const float denom = sq * sq + sk * sk;
    const float inv = 1.0f / denom;
    const float e = __expf(-d2 * inv);
    const float loc = sqrtf(2.0f * sq * sk * inv);
    const float c = __cosf(tpq[d] - tpk[d]);
    acc += beq[d] * bek[d] * loc * e * c;
  }
  kernS[((size_t)b * LL + q) * LL + k] = acc * INV_E8;
}

// ---------------------------------------------------------------------------
// fp32 tiled GEMM: C[M,N] = A[M,K] @ W[K,N] + bias[N], optional ReLU.
// 64x64 tile, BK=16, 256 threads, 4x4 micro-tile.
// M,N,K multiples of 64/16 (guaranteed here).
// ---------------------------------------------------------------------------
template <bool RELU>
__global__ __launch_bounds__(256) void gemm_kernel(
    const float* __restrict__ A, const float* __restrict__ W,
    const float* __restrict__ bias, float* __restrict__ C,
    int M, int N, int K) {
  __shared__ float As[16][64];
  __shared__ float Bs[16][64];
  const int tid = threadIdx.x;
  const int tx = tid & 15, ty = tid >> 4;
  const int colBase = blockIdx.x * 64;
  const int rowBase = blockIdx.y * 64;
  const int aRow = tid >> 2;
  const int aK = (tid & 3) * 4;
  const int bK = tid >> 4;
  const int bN = (tid & 15) * 4;

  float acc[4][4] = {};

  for (int k0 = 0; k0 < K; k0 += 16) {
    const float4 a4 = *reinterpret_cast<const float4*>(
        A + (size_t)(rowBase + aRow) * K + (k0 + aK));
    const float4 b4 = *reinterpret_cast<const float4*>(
        W + (size_t)(k0 + bK) * N + (colBase + bN));
    __syncthreads();
    As[aK + 0][aRow] = a4.x;
    As[aK + 1][aRow] = a4.y;
    As[aK + 2][aRow] = a4.z;
    As[aK + 3][aRow] = a4.w;
    *reinterpret_cast<float4*>(&Bs[bK][bN]) = b4;
    __syncthreads();
#pragma unroll
    for (int kk = 0; kk < 16; ++kk) {
      const float a0 = As[kk][ty * 4 + 0];
      const float a1 = As[kk][ty * 4 + 1];
      const float a2 = As[kk][ty * 4 + 2];
      const float a3 = As[kk][ty * 4 + 3];
      const float b0 = Bs[kk][tx * 4 + 0];
      const float b1 = Bs[kk][tx * 4 + 1];
      const float b2 = Bs[kk][tx * 4 + 2];
      const float b3 = Bs[kk][tx * 4 + 3];
      acc[0][0] += a0 * b0; acc[0][1] += a0 * b1; acc[0][2] += a0 * b2; acc[0][3] += a0 * b3;
      acc[1][0] += a1 * b0; acc[1][1] += a1 * b1; acc[1][2] += a1 * b2; acc[1][3] += a1 * b3;
      acc[2][0] += a2 * b0; acc[2][1] += a2 * b1; acc[2][2] += a2 * b2; acc[2][3] += a2 * b3;
      acc[3][0] += a3 * b0; acc[3][1] += a3 * b1; acc[3][2] += a3 * b2; acc[3][3] += a3 * b3;
    }
  }

  const float4 bi = *reinterpret_cast<const float4*>(bias + colBase + tx * 4);
  const float bv[4] = {bi.x, bi.y, bi.z, bi.w};
#pragma unroll
  for (int i = 0; i < 4; ++i) {
    float4 o;
#pragma unroll
    for (int j = 0; j < 4; ++j) {
      float v = acc[i][j] + bv[j];
      if (RELU) v = fmaxf(v, 0.f);
      (&o.x)[j] = v;
    }
    *reinterpret_cast<float4*>(C + (size_t)(rowBase + ty * 4 + i) * N + colBase + tx * 4) = o;
  }
}

// ---------------------------------------------------------------------------
// Fused attention: per block handles TQ=8 q rows for one (b,h).
// logits (incl. kern bias) -> softmax -> ctx, all in LDS.
// grid (LL/TQ, NH, BB), 256 threads.
// ---------------------------------------------------------------------------
constexpr int TQ = 8;

__global__ __launch_bounds__(256) void attn_kernel(
    const float* __restrict__ Q, const float* __restrict__ K,
    const float* __restrict__ V, const float* __restrict__ kernS,
    float* __restrict__ ctx) {
  const int qt = blockIdx.x;
  const int h = blockIdx.y;
  const int b = blockIdx.z;
  const int tid = threadIdx.x;
  const int q0 = qt * TQ;

  __shared__ float qs[TQ][DHD];
  __shared__ float ls[TQ][LL];
  __shared__ float red[4][TQ][DHD];
  __shared__ float invS[TQ];

  if (tid < TQ * 16) {
    const int qq = tid >> 4;
    const int d4 = (tid & 15) * 4;
    *reinterpret_cast<float4*>(&qs[qq][d4]) = *reinterpret_cast<const float4*>(
        Q + ((size_t)(b * LL + q0 + qq)) * DM + h * DHD + d4);
  }
  __syncthreads();

  // phase 1: logits
  for (int kk = tid; kk < LL; kk += 256) {
    const float* krow = K + ((size_t)(b * LL + kk)) * DM + h * DHD;
    float dot[TQ] = {};
#pragma unroll
    for (int d4 = 0; d4 < 16; ++d4) {
      const float4 kv = *reinterpret_cast<const float4*>(krow + d4 * 4);
#pragma unroll
      for (int qq = 0; qq < TQ; ++qq) {
        dot[qq] += qs[qq][d4 * 4 + 0] * kv.x + qs[qq][d4 * 4 + 1] * kv.y +
                   qs[qq][d4 * 4 + 2] * kv.z + qs[qq][d4 * 4 + 3] * kv.w;
      }
    }
#pragma unroll
    for (int qq = 0; qq < TQ; ++qq) {
      ls[qq][kk] = dot[qq] * 0.125f + kernS[((size_t)b * LL + q0 + qq) * LL + kk];
    }
  }
  __syncthreads();

  // softmax: 8 rows x 32 lanes
  {
    const int row = tid >> 5;
    const int l32 = tid & 31;
    float m = -1e30f;
#pragma unroll
    for (int j = 0; j < 16; ++j) m = fmaxf(m, ls[row][l32 + j * 32]);
#pragma unroll
    for (int s = 16; s; s >>= 1) m = fmaxf(m, __shfl_xor(m, s, 32));
    float sum = 0.f;
#pragma unroll
    for (int j = 0; j < 16; ++j) {
      const float e = __expf(ls[row][l32 + j * 32] - m);
      ls[row][l32 + j * 32] = e;
      sum += e;
    }
#pragma unroll
    for (int s = 16; s; s >>= 1) sum += __shfl_xor(sum, s, 32);
    if (l32 == 0) invS[row] = 1.0f / sum;
  }
  __syncthreads();

  // phase 2: ctx = p @ V
  const int d = tid & 63;
  const int c = tid >> 6;
  float acc[TQ] = {};
  for (int kk = c * 128; kk < c * 128 + 128; ++kk) {
    const float vv = V[((size_t)(b * LL + kk)) * DM + h * DHD + d];
#pragma unroll
    for (int qq = 0; qq < TQ; ++qq) acc[qq] += ls[qq][kk] * vv;
  }
#pragma unroll
  for (int qq = 0; qq < TQ; ++qq) red[c][qq][d] = acc[qq];
  __syncthreads();
  if (c == 0) {
#pragma unroll
    for (int qq = 0; qq < TQ; ++qq) {
      const float r = (red[0][qq][d] + red[1][qq][d]) + (red[2][qq][d] + red[3][qq][d]);
      ctx[((size_t)(b * LL + q0 + qq)) * DM + h * DHD + d] = r * invS[qq];
    }
  }
}

// ---------------------------------------------------------------------------
// Fused residual + LayerNorm: Out = LN(X + R) * g + b.
// One wave per row; 256 threads = 4 rows per block; grid ROWS/4.
// ---------------------------------------------------------------------------
__global__ __launch_bounds__(256) void resid_ln_kernel(
    const float* __restrict__ X, const float* __restrict__ R,
    const float* __restrict__ g, const float* __restrict__ bta,
    float* __restrict__ Out) {
  const int row = blockIdx.x * 4 + (threadIdx.x >> 6);
  const int lane = threadIdx.x & 63;
  const float* x = X + (size_t)row * DM;
  const float* r = R + (size_t)row * DM;

  float v[8];
  float s = 0.f;
#pragma unroll
  for (int j = 0; j < 2; ++j) {
    const float4 a = *reinterpret_cast<const float4*>(x + lane * 8 + j * 4);
    const float4 c = *reinterpret_cast<const float4*>(r + lane * 8 + j * 4);
    v[j * 4 + 0] = a.x + c.x;
    v[j * 4 + 1] = a.y + c.y;
    v[j * 4 + 2] = a.z + c.z;
    v[j * 4 + 3] = a.w + c.w;
    s += v[j * 4 + 0] + v[j * 4 + 1] + v[j * 4 + 2] + v[j * 4 + 3];
  }
#pragma unroll
  for (int m = 1; m < 64; m <<= 1) s += __shfl_xor(s, m, 64);
  const float mean = s * (1.f / DM);
  float var = 0.f;
#pragma unroll
  for (int j = 0; j < 8; ++j) {
    const float dlt = v[j] - mean;
    var += dlt * dlt;
  }
#pragma unroll
  for (int m = 1; m < 64; m <<= 1) var += __shfl_xor(var, m, 64);
  var *= (1.f / DM);
  const float inv = 1.0f / sqrtf(var + 1e-6f);

#pragma unroll
  for (int j = 0; j < 2; ++j) {
    const float4 gg = *reinterpret_cast<const float4*>(g + lane * 8 + j * 4);
    const float4 bb = *reinterpret_cast<const float4*>(bta + lane * 8 + j * 4);
    float4 o;
    o.x = (v[j * 4 + 0] - mean) * inv * gg.x + bb.x;
    o.y = (v[j * 4 + 1] - mean) * inv * gg.y + bb.y;
    o.z = (v[j * 4 + 2] - mean) * inv * gg.z + bb.z;
    o.w = (v[j * 4 + 3] - mean) * inv * gg.w + bb.w;
    *reinterpret_cast<float4*>(Out + (size_t)row * DM + lane * 8 + j * 4) = o;
  }
}

// ---------------------------------------------------------------------------
// launch
// ---------------------------------------------------------------------------
extern "C" void kernel_launch(void* const* d_in, const int* in_sizes, int n_in,
                              void* d_out, int out_size, void* d_ws, size_t ws_size,
                              hipStream_t stream) {
  const float* x_in = (const float*)d_in[0];
  const float* t = (const float*)d_in[1];
  const float* wq = (const float*)d_in[2];
  const float* bq = (const float*)d_in[3];
  const float* wk = (const float*)d_in[4];
  const float* bk = (const float*)d_in[5];
  const float* wv = (const float*)d_in[6];
  const float* bv = (const float*)d_in[7];
  const float* wo = (const float*)d_in[8];
  const float* bo = (const float*)d_in[9];
  const float* w1 = (const float*)d_in[10];
  const float* b1 = (const float*)d_in[11];
  const float* w2 = (const float*)d_in[12];
  const float* b2 = (const float*)d_in[13];
  const float* ln1g = (const float*)d_in[14];
  const float* ln1b = (const float*)d_in[15];
  const float* ln2g = (const float*)d_in[16];
  const float* ln2b = (const float*)d_in[17];
  const float* pw1 = (const float*)d_in[18];
  const float* pb1 = (const float*)d_in[19];
  const float* pw2 = (const float*)d_in[20];
  const float* pb2 = (const float*)d_in[21];
  const float* sw1 = (const float*)d_in[22];
  const float* sb1 = (const float*)d_in[23];
  const float* sw2 = (const float*)d_in[24];
  const float* sb2 = (const float*)d_in[25];
  const float* bw1 = (const float*)d_in[26];
  const float* bb1 = (const float*)d_in[27];
  const float* bw2 = (const float*)d_in[28];
  const float* bb2 = (const float*)d_in[29];

  float* ws = (float*)d_ws;
  size_t off = 0;
  auto alloc = [&](size_t n) {
    float* p = ws + off;
    off += n;
    return p;
  };
  float* tpb = alloc((size_t)ROWS * TD);
  float* sgb = alloc((size_t)ROWS * TD);
  float* beb = alloc((size_t)ROWS * TD);
  float* kernS = alloc((size_t)BB * LL * LL);
  float* qb = alloc((size_t)ROWS * DM);
  float* kb = alloc((size_t)ROWS * DM);
  float* vb = alloc((size_t)ROWS * DM);
  float* cb = alloc((size_t)ROWS * DM);
  float* ao = alloc((size_t)ROWS * DM);
  float* xb = alloc((size_t)ROWS * DM);
  float* hb = alloc((size_t)ROWS * FF);
  float* fb = ao;  // reuse: ao consumed by LN1 before FFN2 writes fb

  for (int i = 0; i < NLAYERS; ++i) {
    const float* xcur = (i == 0) ? x_in : xb;
    float* ln2_out = (i == NLAYERS - 1) ? (float*)d_out : xb;

    small_ffn_kernel<<<ROWS / 256, 256, 0, stream>>>(
        t, pw1 + i * TD, pb1 + i * TD, pw2 + i * TD * TD, pb2 + i * TD,
        sw1 + i * TD, sb1 + i * TD, sw2 + i * TD * TD, sb2 + i * TD,
        bw1 + i * TD, bb1 + i * TD, bw2 + i * TD * TD, bb2 + i * TD,
        tpb, sgb, beb);

    kern_kernel<<<dim3(LL / 256, LL, BB), 256, 0, stream>>>(t, tpb, sgb, beb, kernS);

    gemm_kernel<false><<<dim3(DM / 64, ROWS / 64), 256, 0, stream>>>(
        xcur, wq + (size_t)i * DM * DM, bq + i * DM, qb, ROWS, DM, DM);
    gemm_kernel<false><<<dim3(DM / 64, ROWS / 64), 256, 0, stream>>>(
        xcur, wk + (size_t)i * DM * DM, bk + i * DM, kb, ROWS, DM, DM);
    gemm_kernel<false><<<dim3(DM / 64, ROWS / 64), 256, 0, stream>>>(
        xcur, wv + (size_t)i * DM * DM, bv + i * DM, vb, ROWS, DM, DM);

    attn_kernel<<<dim3(LL / TQ, NH, BB), 256, 0, stream>>>(qb, kb, vb, kernS, cb);

    gemm_kernel<false><<<dim3(DM / 64, ROWS / 64), 256, 0, stream>>>(
        cb, wo + (size_t)i * DM * DM, bo + i * DM, ao, ROWS, DM, DM);

    resid_ln_kernel<<<ROWS / 4, 256, 0, stream>>>(
        xcur, ao, ln1g + i * DM, ln1b + i * DM, xb);

    gemm_kernel<true><<<dim3(FF / 64, ROWS / 64), 256, 0, stream>>>(
        xb, w1 + (size_t)i * DM * FF, b1 + i * FF, hb, ROWS, FF, DM);
    gemm_kernel<false><<<dim3(DM / 64, ROWS / 64), 256, 0, stream>>>(
        hb, w2 + (size_t)i * FF * DM, b2 + i * DM, fb, ROWS, DM, FF);

    resid_ln_kernel<<<ROWS / 4, 256, 0, stream>>>(
        xb, fb, ln2g + i * DM, ln2b + i * DM, ln2_out);
  }
}

// Round 2
// 1328.759 us; speedup vs baseline: 1.2275x; 1.2275x over previous
//
#include <hip/hip_runtime.h>
#include <hip/hip_bf16.h>

#define DEV_INLINE __device__ __forceinline__

constexpr int NLAYERS = 2;
constexpr int DM = 512;
constexpr int NH = 8;
constexpr int DHD = 64;
constexpr int FF = 2048;
constexpr int TD = 8;
constexpr int BB = 8;
constexpr int LL = 512;
constexpr int ROWS = BB * LL;  // 4096
constexpr int QKVN = 3 * DM;   // 1536

constexpr float TWO_PI_F = 6.28318530717958647692f;
constexpr float INV_E8 = 3.3546262790251185e-4f;  // e^-8

typedef __attribute__((ext_vector_type(8))) short short8v;
typedef __attribute__((ext_vector_type(4))) float f32x4;

DEV_INLINE unsigned short bf16_rne(float x) {
  unsigned int u = __float_as_uint(x);
  unsigned int r = (u + 0x7fffu + ((u >> 16) & 1u)) >> 16;
  return (unsigned short)r;
}
DEV_INLINE float bf16_to_f(unsigned short h) {
  return __uint_as_float(((unsigned int)h) << 16);
}
DEV_INLINE void split_bf16(float x, unsigned short& h, unsigned short& l) {
  h = bf16_rne(x);
  float lo = x - bf16_to_f(h);
  l = bf16_rne(lo);
}

// ---------------------------------------------------------------------------
// Small FFNs on t
// ---------------------------------------------------------------------------
DEV_INLINE void ffn2_small(float tv,
                           const float* __restrict__ w1, const float* __restrict__ b1,
                           const float* __restrict__ w2, const float* __restrict__ b2,
                           float* out) {
  float h[TD];
#pragma unroll
  for (int d = 0; d < TD; ++d) h[d] = fmaxf(tv * w1[d] + b1[d], 0.f);
#pragma unroll
  for (int j = 0; j < TD; ++j) {
    float acc = b2[j];
#pragma unroll
    for (int d = 0; d < TD; ++d) acc += h[d] * w2[d * TD + j];
    out[j] = fmaxf(acc, 0.f);
  }
}

__global__ __launch_bounds__(256) void small_ffn_kernel(
    const float* __restrict__ t,
    const float* __restrict__ pw1, const float* __restrict__ pb1,
    const float* __restrict__ pw2, const float* __restrict__ pb2,
    const float* __restrict__ sw1, const float* __restrict__ sb1,
    const float* __restrict__ sw2, const float* __restrict__ sb2,
    const float* __restrict__ bw1, const float* __restrict__ bb1,
    const float* __restrict__ bw2, const float* __restrict__ bb2,
    float* __restrict__ tp, float* __restrict__ sg, float* __restrict__ be) {
  const int i = blockIdx.x * 256 + threadIdx.x;
  if (i >= ROWS) return;
  const float tv = t[i];
  float o[TD];
  ffn2_small(tv, pw1, pb1, pw2, pb2, o);
#pragma unroll
  for (int d = 0; d < TD; ++d) tp[(size_t)i * TD + d] = TWO_PI_F * o[d] * tv;
  ffn2_small(tv, sw1, sb1, sw2, sb2, o);
#pragma unroll
  for (int d = 0; d < TD; ++d) sg[(size_t)i * TD + d] = o[d] + 1e-6f;
  ffn2_small(tv, bw1, bb1, bw2, bb2, o);
#pragma unroll
  for (int d = 0; d < TD; ++d) be[(size_t)i * TD + d] = o[d];
}

// ---------------------------------------------------------------------------
// kern kernel
// ---------------------------------------------------------------------------
DEV_INLINE void load8(const float* __restrict__ p, float* o) {
  float4 a = *reinterpret_cast<const float4*>(p);
  float4 b = *reinterpret_cast<const float4*>(p + 4);
  o[0] = a.x; o[1] = a.y; o[2] = a.z; o[3] = a.w;
  o[4] = b.x; o[5] = b.y; o[6] = b.z; o[7] = b.w;
}

__global__ __launch_bounds__(256) void kern_kernel(
    const float* __restrict__ t, const float* __restrict__ tp,
    const float* __restrict__ sg, const float* __restrict__ be,
    float* __restrict__ kernS) {
  const int k = blockIdx.x * 256 + threadIdx.x;
  const int q = blockIdx.y;
  const int b = blockIdx.z;
  const size_t iq = (size_t)b * LL + q;
  const size_t ik = (size_t)b * LL + k;
  const float tq = t[iq], tk = t[ik];
  const float diff = tq - tk;
  const float d2 = diff * diff;

  float tpq[TD], sgq[TD], beq[TD], tpk[TD], sgk[TD], bek[TD];
  load8(tp + iq * TD, tpq);
  load8(sg + iq * TD, sgq);
  load8(be + iq * TD, beq);
  load8(tp + ik * TD, tpk);
  load8(sg + ik * TD, sgk);
  load8(be + ik * TD, bek);

  float acc = 0.f;
#pragma unroll
  for (int d = 0; d < TD; ++d) {
    const float sq = sgq[d], sk = sgk[d];
    const float denom = sq * sq + sk * sk;
    const float inv = 1.0f / denom;
    const float e = __expf(-d2 * inv);
    const float loc = sqrtf(2.0f * sq * sk * inv);
    const float c = __cosf(tpq[d] - tpk[d]);
    acc += beq[d] * bek[d] * loc * e * c;
  }
  kernS[((size_t)b * LL + q) * LL + k] = acc * INV_E8;
}

// ---------------------------------------------------------------------------
// Weight transpose + hi/lo bf16 decompose: W[K][N] fp32 -> Thi/Tlo[N][K] bf16
// grid (K/32, N/32), 256 threads
// ---------------------------------------------------------------------------
__global__ __launch_bounds__(256) void td_kernel(
    const float* __restrict__ W, unsigned short* __restrict__ Thi,
    unsigned short* __restrict__ Tlo, int K, int N) {
  __shared__ float tile[32][33];
  const int k0 = blockIdx.x * 32, n0 = blockIdx.y * 32;
  const int tx = threadIdx.x & 31, ty = threadIdx.x >> 5;
#pragma unroll
  for (int i = 0; i < 4; ++i)
    tile[ty + i * 8][tx] = W[(size_t)(k0 + ty + i * 8) * N + n0 + tx];
  __syncthreads();
#pragma unroll
  for (int i = 0; i < 4; ++i) {
    const int n = n0 + ty + i * 8;
    const float v = tile[tx][ty + i * 8];
    unsigned short h, l;
    split_bf16(v, h, l);
    Thi[(size_t)n * K + k0 + tx] = h;
    Tlo[(size_t)n * K + k0 + tx] = l;
  }
}

// ---------------------------------------------------------------------------
// Elementwise hi/lo decompose (for layer-0 x). 4 elems/thread.
// ---------------------------------------------------------------------------
__global__ __launch_bounds__(256) void decomp_kernel(
    const float* __restrict__ X, unsigned short* __restrict__ Hi,
    unsigned short* __restrict__ Lo, int n4) {
  const int i = blockIdx.x * 256 + threadIdx.x;
  if (i >= n4) return;
  const float4 v = *reinterpret_cast<const float4*>(X + (size_t)i * 4);
  unsigned short h0, h1, h2, h3, l0, l1, l2, l3;
  split_bf16(v.x, h0, l0);
  split_bf16(v.y, h1, l1);
  split_bf16(v.z, h2, l2);
  split_bf16(v.w, h3, l3);
  uint2 hv, lv;
  hv.x = (unsigned)h0 | ((unsigned)h1 << 16);
  hv.y = (unsigned)h2 | ((unsigned)h3 << 16);
  lv.x = (unsigned)l0 | ((unsigned)l1 << 16);
  lv.y = (unsigned)l2 | ((unsigned)l3 << 16);
  *reinterpret_cast<uint2*>(Hi + (size_t)i * 4) = hv;
  *reinterpret_cast<uint2*>(Lo + (size_t)i * 4) = lv;
}

__global__ __launch_bounds__(256) void qkvbias_kernel(
    const float* __restrict__ bq, const float* __restrict__ bk,
    const float* __restrict__ bv, float* __restrict__ out) {
  const int i = blockIdx.x * 256 + threadIdx.x;
  if (i >= QKVN) return;
  out[i] = i < DM ? bq[i] : (i < 2 * DM ? bk[i - DM] : bv[i - 2 * DM]);
}

// ---------------------------------------------------------------------------
// Split-bf16 MFMA GEMM: C = Ahi@B + Alo@Bhi + Ahi@Blo (+bias, opt relu)
// A: [M][K] bf16 row-major (hi/lo). B: [N][K] bf16 (transposed, hi/lo).
// BM=128, BK=64, 256 threads (4 waves). BN template {64,128}.
// LDS XOR-swizzled (granule ^= row&7) for conflict-minimal ds_read_b128.
// ---------------------------------------------------------------------------
template <int BN, bool RELU, bool SPLIT_OUT>
__global__ __launch_bounds__(256) void gemm_mfma(
    const unsigned short* __restrict__ Ahi, const unsigned short* __restrict__ Alo,
    const unsigned short* __restrict__ Bhi, const unsigned short* __restrict__ Blo,
    const float* __restrict__ bias, float* __restrict__ C,
    unsigned short* __restrict__ Chi, unsigned short* __restrict__ Clo,
    int M, int N, int K) {
  constexpr int BM = 128, BK = 64;
  constexpr int WN = (BN == 128) ? 2 : 1;
  constexpr int WM = 4 / WN;
  constexpr int WT_M = BM / WM;   // 64 or 32
  constexpr int WT_N = BN / WN;   // 64
  constexpr int MI = WT_M / 16;   // 4 or 2
  constexpr int NI = WT_N / 16;   // 4
  constexpr int A_ITERS = BM * BK / (256 * 8);  // 4
  constexpr int B_ITERS = BN * BK / (256 * 8);  // 2 or 4

  __shared__ unsigned short As[BM * BK];
  __shared__ unsigned short Bs[BN * BK];

  const int tid = threadIdx.x;
  const int lane = tid & 63;
  const int wid = tid >> 6;
  const int wr = wid / WN, wc = wid % WN;
  const int rowBase = blockIdx.y * BM;
  const int colBase = blockIdx.x * BN;
  const int l15 = lane & 15, l4 = lane >> 4;

  f32x4 acc[MI][NI] = {};

  const int ktiles = K / BK;
  const int ntiles = 3 * ktiles;

  uint4 aReg[A_ITERS], bReg[B_ITERS];

  // prefetch tile 0 (segment 0: Ahi x Bhi)
#pragma unroll
  for (int it = 0; it < A_ITERS; ++it) {
    const int idx = it * 256 + tid;
    const int r = idx >> 3, g = idx & 7;
    aReg[it] = *reinterpret_cast<const uint4*>(Ahi + (size_t)(rowBase + r) * K + g * 8);
  }
#pragma unroll
  for (int it = 0; it < B_ITERS; ++it) {
    const int idx = it * 256 + tid;
    const int r = idx >> 3, g = idx & 7;
    bReg[it] = *reinterpret_cast<const uint4*>(Bhi + (size_t)(colBase + r) * K + g * 8);
  }

  for (int t = 0; t < ntiles; ++t) {
    __syncthreads();
#pragma unroll
    for (int it = 0; it < A_ITERS; ++it) {
      const int idx = it * 256 + tid;
      const int r = idx >> 3, g = idx & 7;
      *reinterpret_cast<uint4*>(&As[(r << 6) + ((g ^ (r & 7)) << 3)]) = aReg[it];
    }
#pragma unroll
    for (int it = 0; it < B_ITERS; ++it) {
      const int idx = it * 256 + tid;
      const int r = idx >> 3, g = idx & 7;
      *reinterpret_cast<uint4*>(&Bs[(r << 6) + ((g ^ (r & 7)) << 3)]) = bReg[it];
    }
    __syncthreads();

    if (t + 1 < ntiles) {
      const int tn = t + 1;
      const int s = tn / ktiles;
      const int k0 = (tn - s * ktiles) * BK;
      const unsigned short* Ab = (s == 1) ? Alo : Ahi;
      const unsigned short* Bb = (s == 2) ? Blo : Bhi;
#pragma unroll
      for (int it = 0; it < A_ITERS; ++it) {
        const int idx = it * 256 + tid;
        const int r = idx >> 3, g = idx & 7;
        aReg[it] = *reinterpret_cast<const uint4*>(Ab + (size_t)(rowBase + r) * K + k0 + g * 8);
      }
#pragma unroll
      for (int it = 0; it < B_ITERS; ++it) {
        const int idx = it * 256 + tid;
        const int r = idx >> 3, g = idx & 7;
        bReg[it] = *reinterpret_cast<const uint4*>(Bb + (size_t)(colBase + r) * K + k0 + g * 8);
      }
    }

#pragma unroll
    for (int ks = 0; ks < 2; ++ks) {
      short8v a[MI], b[NI];
#pragma unroll
      for (int mi = 0; mi < MI; ++mi) {
        const int r = wr * WT_M + mi * 16 + l15;
        const int g = (ks * 4 + l4) ^ (r & 7);
        a[mi] = *reinterpret_cast<const short8v*>(&As[(r << 6) + (g << 3)]);
      }
#pragma unroll
      for (int ni = 0; ni < NI; ++ni) {
        const int r = wc * WT_N + ni * 16 + l15;
        const int g = (ks * 4 + l4) ^ (r & 7);
        b[ni] = *reinterpret_cast<const short8v*>(&Bs[(r << 6) + (g << 3)]);
      }
#pragma unroll
      for (int mi = 0; mi < MI; ++mi)
#pragma unroll
        for (int ni = 0; ni < NI; ++ni)
          acc[mi][ni] = __builtin_amdgcn_mfma_f32_16x16x32_bf16(a[mi], b[ni], acc[mi][ni], 0, 0, 0);
    }
  }

#pragma unroll
  for (int mi = 0; mi < MI; ++mi) {
#pragma unroll
    for (int ni = 0; ni < NI; ++ni) {
      const int col = colBase + wc * WT_N + ni * 16 + l15;
      const float bv = bias[col];
#pragma unroll
      for (int j = 0; j < 4; ++j) {
        const int row = rowBase + wr * WT_M + mi * 16 + l4 * 4 + j;
        float v = acc[mi][ni][j] + bv;
        if (RELU) v = fmaxf(v, 0.f);
        if (SPLIT_OUT) {
          unsigned short h, l;
          split_bf16(v, h, l);
          Chi[(size_t)row * N + col] = h;
          Clo[(size_t)row * N + col] = l;
        } else {
          C[(size_t)row * N + col] = v;
        }
      }
    }
  }
}

// ---------------------------------------------------------------------------
// K transpose: qkvb k-slice -> ktb[bh][d][kk]  (fp32)
// grid (LL/32, DHD/32, BB*NH), 256 threads
// ---------------------------------------------------------------------------
__global__ __launch_bounds__(256) void txp_kernel(
    const float* __restrict__ qkvb, float* __restrict__ ktb) {
  __shared__ float tile[32][33];
  const int bh = blockIdx.z;
  const int b = bh >> 3, h = bh & 7;
  const int kk0 = blockIdx.x * 32, d0 = blockIdx.y * 32;
  const int tx = threadIdx.x & 31, ty = threadIdx.x >> 5;
#pragma unroll
  for (int i = 0; i < 4; ++i) {
    const int kk = kk0 + ty + i * 8;
    tile[ty + i * 8][tx] = qkvb[(size_t)(b * LL + kk) * QKVN + DM + h * DHD + d0 + tx];
  }
  __syncthreads();
#pragma unroll
  for (int i = 0; i < 4; ++i) {
    const int d = d0 + ty + i * 8;
    ktb[((size_t)bh * DHD + d) * LL + kk0 + tx] = tile[tx][ty + i * 8];
  }
}

// ---------------------------------------------------------------------------
// Fused attention (vector fp32): TQ=8 q rows per block, transposed LDS.
// grid (LL/TQ, NH, BB), 256 threads. Writes ctx as bf16 hi/lo.
// ---------------------------------------------------------------------------
constexpr int TQ = 8;

__global__ __launch_bounds__(256) void attn_kernel(
    const float* __restrict__ qkvb, const float* __restrict__ ktb,
    const float* __restrict__ kernS,
    unsigned short* __restrict__ ctxhi, unsigned short* __restrict__ ctxlo) {
  const int qt = blockIdx.x;
  const int h = blockIdx.y;
  const int b = blockIdx.z;
  const int tid = threadIdx.x;
  const int q0 = qt * TQ;

  __shared__ float qst[DHD][TQ];
  __shared__ float lst[LL][TQ];
  __shared__ float red[4][TQ][DHD];
  __shared__ float invS[TQ];

  // load q transposed
  {
    const int d = tid & 63;
    const int qq0 = tid >> 6;
#pragma unroll
    for (int rep = 0; rep < 2; ++rep) {
      const int qq = qq0 + rep * 4;
      qst[d][qq] = qkvb[(size_t)(b * LL + q0 + qq) * QKVN + h * DHD + d];
    }
  }
  __syncthreads();

  // phase 1: logits (thread handles kk=tid and kk+256)
  {
    const int kk = tid;
    const float* kcol = ktb + (size_t)(b * NH + h) * DHD * LL;
    float dot0[TQ] = {}, dot1[TQ] = {};
#pragma unroll 4
    for (int d = 0; d < DHD; ++d) {
      const float ka = kcol[(size_t)d * LL + kk];
      const float kb2 = kcol[(size_t)d * LL + kk + 256];
      const float4 qa = *reinterpret_cast<const float4*>(&qst[d][0]);
      const float4 qb2 = *reinterpret_cast<const float4*>(&qst[d][4]);
      dot0[0] += qa.x * ka; dot0[1] += qa.y * ka; dot0[2] += qa.z * ka; dot0[3] += qa.w * ka;
      dot0[4] += qb2.x * ka; dot0[5] += qb2.y * ka; dot0[6] += qb2.z * ka; dot0[7] += qb2.w * ka;
      dot1[0] += qa.x * kb2; dot1[1] += qa.y * kb2; dot1[2] += qa.z * kb2; dot1[3] += qa.w * kb2;
      dot1[4] += qb2.x * kb2; dot1[5] += qb2.y * kb2; dot1[6] += qb2.z * kb2; dot1[7] += qb2.w * kb2;
    }
#pragma unroll
    for (int qq = 0; qq < TQ; ++qq) {
      const size_t kbase = ((size_t)b * LL + q0 + qq) * LL;
      lst[kk][qq] = dot0[qq] * 0.125f + kernS[kbase + kk];
      lst[kk + 256][qq] = dot1[qq] * 0.125f + kernS[kbase + kk + 256];
    }
  }
  __syncthreads();

  // softmax: 8 rows x 32 lanes
  {
    const int row = tid >> 5;
    const int l32 = tid & 31;
    float m = -1e30f;
#pragma unroll
    for (int j = 0; j < 16; ++j) m = fmaxf(m, lst[l32 + j * 32][row]);
#pragma unroll
    for (int s = 16; s; s >>= 1) m = fmaxf(m, __shfl_xor(m, s, 32));
    float sum = 0.f;
#pragma unroll
    for (int j = 0; j < 16; ++j) {
      const float e = __expf(lst[l32 + j * 32][row] - m);
      lst[l32 + j * 32][row] = e;
      sum += e;
    }
#pragma unroll
    for (int s = 16; s; s >>= 1) sum += __shfl_xor(sum, s, 32);
    if (l32 == 0) invS[row] = 1.0f / sum;
  }
  __syncthreads();

  // phase 2: ctx = p @ V
  const int d = tid & 63;
  const int c = tid >> 6;
  float acc[TQ] = {};
  for (int kk = c * 128; kk < c * 128 + 128; ++kk) {
    const float vv = qkvb[(size_t)(b * LL + kk) * QKVN + 2 * DM + h * DHD + d];
    const float4 pa = *reinterpret_cast<const float4*>(&lst[kk][0]);
    const float4 pb2 = *reinterpret_cast<const float4*>(&lst[kk][4]);
    acc[0] += pa.x * vv; acc[1] += pa.y * vv; acc[2] += pa.z * vv; acc[3] += pa.w * vv;
    acc[4] += pb2.x * vv; acc[5] += pb2.y * vv; acc[6] += pb2.z * vv; acc[7] += pb2.w * vv;
  }
#pragma unroll
  for (int qq = 0; qq < TQ; ++qq) red[c][qq][d] = acc[qq];
  __syncthreads();
  if (c == 0) {
#pragma unroll
    for (int qq = 0; qq < TQ; ++qq) {
      const float r = ((red[0][qq][d] + red[1][qq][d]) + (red[2][qq][d] + red[3][qq][d])) * invS[qq];
      unsigned short hh, ll;
      split_bf16(r, hh, ll);
      const size_t o = (size_t)(b * LL + q0 + qq) * DM + h * DHD + d;
      ctxhi[o] = hh;
      ctxlo[o] = ll;
    }
  }
}

// ---------------------------------------------------------------------------
// Fused residual + LayerNorm; writes fp32 + bf16 hi/lo decomposition.
// ---------------------------------------------------------------------------
__global__ __launch_bounds__(256) void resid_ln_kernel(
    const float* __restrict__ X, const float* __restrict__ R,
    const float* __restrict__ g, const float* __restrict__ bta,
    float* __restrict__ Out, unsigned short* __restrict__ OutHi,
    unsigned short* __restrict__ OutLo) {
  const int row = blockIdx.x * 4 + (threadIdx.x >> 6);
  const int lane = threadIdx.x & 63;
  const float* x = X + (size_t)row * DM;
  const float* r = R + (size_t)row * DM;

  float v[8];
  float s = 0.f;
#pragma unroll
  for (int j = 0; j < 2; ++j) {
    const float4 a = *reinterpret_cast<const float4*>(x + lane * 8 + j * 4);
    const float4 c = *reinterpret_cast<const float4*>(r + lane * 8 + j * 4);
    v[j * 4 + 0] = a.x + c.x;
    v[j * 4 + 1] = a.y + c.y;
    v[j * 4 + 2] = a.z + c.z;
    v[j * 4 + 3] = a.w + c.w;
    s += v[j * 4 + 0] + v[j * 4 + 1] + v[j * 4 + 2] + v[j * 4 + 3];
  }
#pragma unroll
  for (int m = 1; m < 64; m <<= 1) s += __shfl_xor(s, m, 64);
  const float mean = s * (1.f / DM);
  float var = 0.f;
#pragma unroll
  for (int j = 0; j < 8; ++j) {
    const float dlt = v[j] - mean;
    var += dlt * dlt;
  }
#pragma unroll
  for (int m = 1; m < 64; m <<= 1) var += __shfl_xor(var, m, 64);
  var *= (1.f / DM);
  const float inv = 1.0f / sqrtf(var + 1e-6f);

  unsigned short hs[8], ls[8];
#pragma unroll
  for (int j = 0; j < 2; ++j) {
    const float4 gg = *reinterpret_cast<const float4*>(g + lane * 8 + j * 4);
    const float4 bb = *reinterpret_cast<const float4*>(bta + lane * 8 + j * 4);
    float4 o;
    o.x = (v[j * 4 + 0] - mean) * inv * gg.x + bb.x;
    o.y = (v[j * 4 + 1] - mean) * inv * gg.y + bb.y;
    o.z = (v[j * 4 + 2] - mean) * inv * gg.z + bb.z;
    o.w = (v[j * 4 + 3] - mean) * inv * gg.w + bb.w;
    *reinterpret_cast<float4*>(Out + (size_t)row * DM + lane * 8 + j * 4) = o;
    split_bf16(o.x, hs[j * 4 + 0], ls[j * 4 + 0]);
    split_bf16(o.y, hs[j * 4 + 1], ls[j * 4 + 1]);
    split_bf16(o.z, hs[j * 4 + 2], ls[j * 4 + 2]);
    split_bf16(o.w, hs[j * 4 + 3], ls[j * 4 + 3]);
  }
  uint4 hv, lv;
  hv.x = (unsigned)hs[0] | ((unsigned)hs[1] << 16);
  hv.y = (unsigned)hs[2] | ((unsigned)hs[3] << 16);
  hv.z = (unsigned)hs[4] | ((unsigned)hs[5] << 16);
  hv.w = (unsigned)hs[6] | ((unsigned)hs[7] << 16);
  lv.x = (unsigned)ls[0] | ((unsigned)ls[1] << 16);
  lv.y = (unsigned)ls[2] | ((unsigned)ls[3] << 16);
  lv.z = (unsigned)ls[4] | ((unsigned)ls[5] << 16);
  lv.w = (unsigned)ls[6] | ((unsigned)ls[7] << 16);
  *reinterpret_cast<uint4*>(OutHi + (size_t)row * DM + lane * 8) = hv;
  *reinterpret_cast<uint4*>(OutLo + (size_t)row * DM + lane * 8) = lv;
}

// ---------------------------------------------------------------------------
// launch
// ---------------------------------------------------------------------------
extern "C" void kernel_launch(void* const* d_in, const int* in_sizes, int n_in,
                              void* d_out, int out_size, void* d_ws, size_t ws_size,
                              hipStream_t stream) {
  const float* x_in = (const float*)d_in[0];
  const float* t = (const float*)d_in[1];
  const float* wq = (const float*)d_in[2];
  const float* bq = (const float*)d_in[3];
  const float* wk = (const float*)d_in[4];
  const float* bk = (const float*)d_in[5];
  const float* wv = (const float*)d_in[6];
  const float* bv = (const float*)d_in[7];
  const float* wo = (const float*)d_in[8];
  const float* bo = (const float*)d_in[9];
  const float* w1 = (const float*)d_in[10];
  const float* b1 = (const float*)d_in[11];
  const float* w2 = (const float*)d_in[12];
  const float* b2 = (const float*)d_in[13];
  const float* ln1g = (const float*)d_in[14];
  const float* ln1b = (const float*)d_in[15];
  const float* ln2g = (const float*)d_in[16];
  const float* ln2b = (const float*)d_in[17];
  const float* pw1 = (const float*)d_in[18];
  const float* pb1 = (const float*)d_in[19];
  const float* pw2 = (const float*)d_in[20];
  const float* pb2 = (const float*)d_in[21];
  const float* sw1 = (const float*)d_in[22];
  const float* sb1 = (const float*)d_in[23];
  const float* sw2 = (const float*)d_in[24];
  const float* sb2 = (const float*)d_in[25];
  const float* bw1 = (const float*)d_in[26];
  const float* bb1 = (const float*)d_in[27];
  const float* bw2 = (const float*)d_in[28];
  const float* bb2 = (const float*)d_in[29];

  char* wsb = (char*)d_ws;
  size_t off = 0;
  auto allocB = [&](size_t bytes) {
    char* p = wsb + off;
    off += (bytes + 255) & ~(size_t)255;
    return p;
  };
  // fp32 buffers
  float* tpb = (float*)allocB(ROWS * TD * 4);
  float* sgb = (float*)allocB(ROWS * TD * 4);
  float* beb = (float*)allocB(ROWS * TD * 4);
  float* kernS = (float*)allocB((size_t)BB * LL * LL * 4);
  float* qkvb = (float*)allocB((size_t)ROWS * QKVN * 4);   // } h hi/lo aliases
  float* ktb = (float*)allocB((size_t)BB * NH * DHD * LL * 4);  // } this region
  float* ao = (float*)allocB((size_t)ROWS * DM * 4);
  float* xb = (float*)allocB((size_t)ROWS * DM * 4);
  float* fb = (float*)allocB((size_t)ROWS * DM * 4);
  float* xn = (float*)allocB((size_t)ROWS * DM * 4);
  float* qkvbias = (float*)allocB(QKVN * 4);
  // bf16 buffers
  unsigned short* qkvwt_hi = (unsigned short*)allocB((size_t)QKVN * DM * 2);
  unsigned short* qkvwt_lo = (unsigned short*)allocB((size_t)QKVN * DM * 2);
  unsigned short* wot_hi = (unsigned short*)allocB((size_t)DM * DM * 2);
  unsigned short* wot_lo = (unsigned short*)allocB((size_t)DM * DM * 2);
  unsigned short* w1t_hi = (unsigned short*)allocB((size_t)FF * DM * 2);
  unsigned short* w1t_lo = (unsigned short*)allocB((size_t)FF * DM * 2);
  unsigned short* w2t_hi = (unsigned short*)allocB((size_t)DM * FF * 2);
  unsigned short* w2t_lo = (unsigned short*)allocB((size_t)DM * FF * 2);
  unsigned short* xhi = (unsigned short*)allocB((size_t)ROWS * DM * 2);
  unsigned short* xlo = (unsigned short*)allocB((size_t)ROWS * DM * 2);
  unsigned short* ctxhi = (unsigned short*)allocB((size_t)ROWS * DM * 2);
  unsigned short* ctxlo = (unsigned short*)allocB((size_t)ROWS * DM * 2);
  // h hi/lo alias over [qkvb, ktb] (dead by FFN1 time; 33.55 MB fits exactly)
  unsigned short* hhi = (unsigned short*)qkvb;
  unsigned short* hlo = hhi + (size_t)ROWS * FF;

  const float* xcur = x_in;

  for (int i = 0; i < NLAYERS; ++i) {
    // weight prep
    td_kernel<<<dim3(16, 16), 256, 0, stream>>>(wq + (size_t)i * DM * DM, qkvwt_hi, qkvwt_lo, DM, DM);
    td_kernel<<<dim3(16, 16), 256, 0, stream>>>(wk + (size_t)i * DM * DM, qkvwt_hi + (size_t)DM * DM, qkvwt_lo + (size_t)DM * DM, DM, DM);
    td_kernel<<<dim3(16, 16), 256, 0, stream>>>(wv + (size_t)i * DM * DM, qkvwt_hi + (size_t)2 * DM * DM, qkvwt_lo + (size_t)2 * DM * DM, DM, DM);
    td_kernel<<<dim3(16, 16), 256, 0, stream>>>(wo + (size_t)i * DM * DM, wot_hi, wot_lo, DM, DM);
    td_kernel<<<dim3(16, 64), 256, 0, stream>>>(w1 + (size_t)i * DM * FF, w1t_hi, w1t_lo, DM, FF);
    td_kernel<<<dim3(64, 16), 256, 0, stream>>>(w2 + (size_t)i * FF * DM, w2t_hi, w2t_lo, FF, DM);
    qkvbias_kernel<<<(QKVN + 255) / 256, 256, 0, stream>>>(bq + i * DM, bk + i * DM, bv + i * DM, qkvbias);

    small_ffn_kernel<<<ROWS / 256, 256, 0, stream>>>(
        t, pw1 + i * TD, pb1 + i * TD, pw2 + i * TD * TD, pb2 + i * TD,
        sw1 + i * TD, sb1 + i * TD, sw2 + i * TD * TD, sb2 + i * TD,
        bw1 + i * TD, bb1 + i * TD, bw2 + i * TD * TD, bb2 + i * TD,
        tpb, sgb, beb);
    kern_kernel<<<dim3(LL / 256, LL, BB), 256, 0, stream>>>(t, tpb, sgb, beb, kernS);

    if (i == 0) {
      decomp_kernel<<<(ROWS * DM / 4 + 255) / 256, 256, 0, stream>>>(x_in, xhi, xlo, ROWS * DM / 4);
    }

    // QKV fused GEMM: [4096][1536]
    gemm_mfma<128, false, false><<<dim3(QKVN / 128, ROWS / 128), 256, 0, stream>>>(
        xhi, xlo, qkvwt_hi, qkvwt_lo, qkvbias, qkvb, nullptr, nullptr, ROWS, QKVN, DM);

    txp_kernel<<<dim3(LL / 32, DHD / 32, BB * NH), 256, 0, stream>>>(qkvb, ktb);

    attn_kernel<<<dim3(LL / TQ, NH, BB), 256, 0, stream>>>(qkvb, ktb, kernS, ctxhi, ctxlo);

    // O projection
    gemm_mfma<64, false, false><<<dim3(DM / 64, ROWS / 128), 256, 0, stream>>>(
        ctxhi, ctxlo, wot_hi, wot_lo, bo + i * DM, ao, nullptr, nullptr, ROWS, DM, DM);

    resid_ln_kernel<<<ROWS / 4, 256, 0, stream>>>(
        xcur, ao, ln1g + i * DM, ln1b + i * DM, xb, xhi, xlo);

    // FFN1 (relu, split bf16 out)
    gemm_mfma<128, true, true><<<dim3(FF / 128, ROWS / 128), 256, 0, stream>>>(
        xhi, xlo, w1t_hi, w1t_lo, b1 + i * FF, nullptr, hhi, hlo, ROWS, FF, DM);

    // FFN2
    gemm_mfma<64, false, false><<<dim3(DM / 64, ROWS / 128), 256, 0, stream>>>(
        hhi, hlo, w2t_hi, w2t_lo, b2 + i * DM, fb, nullptr, nullptr, ROWS, DM, FF);

    float* ln2_out = (i == NLAYERS - 1) ? (float*)d_out : xn;
    resid_ln_kernel<<<ROWS / 4, 256, 0, stream>>>(
        xb, fb, ln2g + i * DM, ln2b + i * DM, ln2_out, xhi, xlo);

    xcur = xn;
  }
}

// Round 3
// 922.777 us; speedup vs baseline: 1.7676x; 1.4400x over previous
//
#include <hip/hip_runtime.h>
#include <hip/hip_bf16.h>

#define DEV_INLINE __device__ __forceinline__

constexpr int NLAYERS = 2;
constexpr int DM = 512;
constexpr int NH = 8;
constexpr int DHD = 64;
constexpr int FF = 2048;
constexpr int TD = 8;
constexpr int BB = 8;
constexpr int LL = 512;
constexpr int ROWS = BB * LL;  // 4096
constexpr int QKVN = 3 * DM;   // 1536

constexpr float TWO_PI_F = 6.28318530717958647692f;
constexpr float INV_E8 = 3.3546262790251185e-4f;  // e^-8

typedef __attribute__((ext_vector_type(8))) short short8v;
typedef __attribute__((ext_vector_type(4))) float f32x4;

DEV_INLINE unsigned short bf16_rne(float x) {
  unsigned int u = __float_as_uint(x);
  unsigned int r = (u + 0x7fffu + ((u >> 16) & 1u)) >> 16;
  return (unsigned short)r;
}
DEV_INLINE float bf16_to_f(unsigned short h) {
  return __uint_as_float(((unsigned int)h) << 16);
}
DEV_INLINE void split_bf16(float x, unsigned short& h, unsigned short& l) {
  h = bf16_rne(x);
  float lo = x - bf16_to_f(h);
  l = bf16_rne(lo);
}

// ---------------------------------------------------------------------------
// Small FFNs on t
// ---------------------------------------------------------------------------
DEV_INLINE void ffn2_small(float tv,
                           const float* __restrict__ w1, const float* __restrict__ b1,
                           const float* __restrict__ w2, const float* __restrict__ b2,
                           float* out) {
  float h[TD];
#pragma unroll
  for (int d = 0; d < TD; ++d) h[d] = fmaxf(tv * w1[d] + b1[d], 0.f);
#pragma unroll
  for (int j = 0; j < TD; ++j) {
    float acc = b2[j];
#pragma unroll
    for (int d = 0; d < TD; ++d) acc += h[d] * w2[d * TD + j];
    out[j] = fmaxf(acc, 0.f);
  }
}

__global__ __launch_bounds__(256) void small_ffn_kernel(
    const float* __restrict__ t,
    const float* __restrict__ pw1, const float* __restrict__ pb1,
    const float* __restrict__ pw2, const float* __restrict__ pb2,
    const float* __restrict__ sw1, const float* __restrict__ sb1,
    const float* __restrict__ sw2, const float* __restrict__ sb2,
    const float* __restrict__ bw1, const float* __restrict__ bb1,
    const float* __restrict__ bw2, const float* __restrict__ bb2,
    float* __restrict__ tp, float* __restrict__ sg, float* __restrict__ be) {
  const int i = blockIdx.x * 256 + threadIdx.x;
  if (i >= ROWS) return;
  const float tv = t[i];
  float o[TD];
  ffn2_small(tv, pw1, pb1, pw2, pb2, o);
#pragma unroll
  for (int d = 0; d < TD; ++d) tp[(size_t)i * TD + d] = TWO_PI_F * o[d] * tv;
  ffn2_small(tv, sw1, sb1, sw2, sb2, o);
#pragma unroll
  for (int d = 0; d < TD; ++d) sg[(size_t)i * TD + d] = o[d] + 1e-6f;
  ffn2_small(tv, bw1, bb1, bw2, bb2, o);
#pragma unroll
  for (int d = 0; d < TD; ++d) be[(size_t)i * TD + d] = o[d];
}

// ---------------------------------------------------------------------------
// kern kernel
// ---------------------------------------------------------------------------
DEV_INLINE void load8(const float* __restrict__ p, float* o) {
  float4 a = *reinterpret_cast<const float4*>(p);
  float4 b = *reinterpret_cast<const float4*>(p + 4);
  o[0] = a.x; o[1] = a.y; o[2] = a.z; o[3] = a.w;
  o[4] = b.x; o[5] = b.y; o[6] = b.z; o[7] = b.w;
}

__global__ __launch_bounds__(256) void kern_kernel(
    const float* __restrict__ t, const float* __restrict__ tp,
    const float* __restrict__ sg, const float* __restrict__ be,
    float* __restrict__ kernS) {
  const int k = blockIdx.x * 256 + threadIdx.x;
  const int q = blockIdx.y;
  const int b = blockIdx.z;
  const size_t iq = (size_t)b * LL + q;
  const size_t ik = (size_t)b * LL + k;
  const float tq = t[iq], tk = t[ik];
  const float diff = tq - tk;
  const float d2 = diff * diff;

  float tpq[TD], sgq[TD], beq[TD], tpk[TD], sgk[TD], bek[TD];
  load8(tp + iq * TD, tpq);
  load8(sg + iq * TD, sgq);
  load8(be + iq * TD, beq);
  load8(tp + ik * TD, tpk);
  load8(sg + ik * TD, sgk);
  load8(be + ik * TD, bek);

  float acc = 0.f;
#pragma unroll
  for (int d = 0; d < TD; ++d) {
    const float sq = sgq[d], sk = sgk[d];
    const float denom = sq * sq + sk * sk;
    const float inv = 1.0f / denom;
    const float e = __expf(-d2 * inv);
    const float loc = sqrtf(2.0f * sq * sk * inv);
    const float c = __cosf(tpq[d] - tpk[d]);
    acc += beq[d] * bek[d] * loc * e * c;
  }
  kernS[((size_t)b * LL + q) * LL + k] = acc * INV_E8;
}

// ---------------------------------------------------------------------------
// Weight transpose + hi/lo bf16 decompose: W[K][N] fp32 -> Thi/Tlo[N][K] bf16
// ---------------------------------------------------------------------------
__global__ __launch_bounds__(256) void td_kernel(
    const float* __restrict__ W, unsigned short* __restrict__ Thi,
    unsigned short* __restrict__ Tlo, int K, int N) {
  __shared__ float tile[32][33];
  const int k0 = blockIdx.x * 32, n0 = blockIdx.y * 32;
  const int tx = threadIdx.x & 31, ty = threadIdx.x >> 5;
#pragma unroll
  for (int i = 0; i < 4; ++i)
    tile[ty + i * 8][tx] = W[(size_t)(k0 + ty + i * 8) * N + n0 + tx];
  __syncthreads();
#pragma unroll
  for (int i = 0; i < 4; ++i) {
    const int n = n0 + ty + i * 8;
    const float v = tile[tx][ty + i * 8];
    unsigned short h, l;
    split_bf16(v, h, l);
    Thi[(size_t)n * K + k0 + tx] = h;
    Tlo[(size_t)n * K + k0 + tx] = l;
  }
}

// ---------------------------------------------------------------------------
// Elementwise hi/lo decompose (for layer-0 x). 4 elems/thread.
// ---------------------------------------------------------------------------
__global__ __launch_bounds__(256) void decomp_kernel(
    const float* __restrict__ X, unsigned short* __restrict__ Hi,
    unsigned short* __restrict__ Lo, int n4) {
  const int i = blockIdx.x * 256 + threadIdx.x;
  if (i >= n4) return;
  const float4 v = *reinterpret_cast<const float4*>(X + (size_t)i * 4);
  unsigned short h0, h1, h2, h3, l0, l1, l2, l3;
  split_bf16(v.x, h0, l0);
  split_bf16(v.y, h1, l1);
  split_bf16(v.z, h2, l2);
  split_bf16(v.w, h3, l3);
  uint2 hv, lv;
  hv.x = (unsigned)h0 | ((unsigned)h1 << 16);
  hv.y = (unsigned)h2 | ((unsigned)h3 << 16);
  lv.x = (unsigned)l0 | ((unsigned)l1 << 16);
  lv.y = (unsigned)l2 | ((unsigned)l3 << 16);
  *reinterpret_cast<uint2*>(Hi + (size_t)i * 4) = hv;
  *reinterpret_cast<uint2*>(Lo + (size_t)i * 4) = lv;
}

__global__ __launch_bounds__(256) void qkvbias_kernel(
    const float* __restrict__ bq, const float* __restrict__ bk,
    const float* __restrict__ bv, float* __restrict__ out) {
  const int i = blockIdx.x * 256 + threadIdx.x;
  if (i >= QKVN) return;
  out[i] = i < DM ? bq[i] : (i < 2 * DM ? bk[i - DM] : bv[i - 2 * DM]);
}

// ---------------------------------------------------------------------------
// Split-bf16 MFMA GEMM, SINGLE K-pass with interleaved hi/lo products:
//   C = Ahi@Bhi + Alo@Bhi + Ahi@Blo (+bias, opt relu)
// A: [M][K] bf16 (hi/lo). B: [N][K] bf16 (transposed, hi/lo).
// BM=128, BK=64, 256 threads (4 waves, 2x2 wave grid), double-buffered LDS,
// ONE barrier per k-tile; next-tile global loads issued a tile ahead.
// XCD-bijective block swizzle (nwg % 8 == 0 for all grids used here).
// ---------------------------------------------------------------------------
template <int BN, bool RELU, bool SPLIT_OUT>
__global__ __launch_bounds__(256) void gemm_mfma(
    const unsigned short* __restrict__ Ahi, const unsigned short* __restrict__ Alo,
    const unsigned short* __restrict__ Bhi, const unsigned short* __restrict__ Blo,
    const float* __restrict__ bias, float* __restrict__ C,
    unsigned short* __restrict__ Chi, unsigned short* __restrict__ Clo,
    int M, int N, int K) {
  constexpr int BM = 128, BK = 64;
  constexpr int WT_M = 64;        // wave tile rows (2 waves along M)
  constexpr int WT_N = BN / 2;    // wave tile cols (2 waves along N)
  constexpr int MI = WT_M / 16;   // 4
  constexpr int NI = WT_N / 16;   // 4 (BN=128) or 2 (BN=64)
  constexpr int A_IT = BM * BK / (256 * 8);  // 4
  constexpr int B_IT = BN * BK / (256 * 8);  // 4 or 2

  __shared__ unsigned short AsH[2][BM * BK];
  __shared__ unsigned short AsL[2][BM * BK];
  __shared__ unsigned short BsH[2][BN * BK];
  __shared__ unsigned short BsL[2][BN * BK];

  // XCD-bijective swizzle: blocks dispatched consecutively (orig) round-robin
  // over 8 XCDs; remap so each XCD owns a contiguous chunk of logical tiles.
  const int nwg = gridDim.x * gridDim.y;
  const int orig = blockIdx.y * gridDim.x + blockIdx.x;
  const int swz = (orig & 7) * (nwg >> 3) + (orig >> 3);
  const int bx = swz % gridDim.x;
  const int by = swz / gridDim.x;

  const int tid = threadIdx.x;
  const int lane = tid & 63;
  const int wid = tid >> 6;
  const int wr = wid >> 1, wc = wid & 1;
  const int rowBase = by * BM;
  const int colBase = bx * BN;
  const int l15 = lane & 15, l4 = lane >> 4;

  // staging geometry: chunk idx = it*256+tid; r = idx>>3, g = tid&7 (const)
  const int sg_ = tid & 7;
  const int srA = tid >> 3;             // row within 32-row group
  const int swg = sg_ ^ (srA & 7);      // swizzled LDS granule (const per thread)

  f32x4 acc[MI][NI] = {};
  const int nt = K / BK;

  uint4 ahR[A_IT], alR[A_IT], bhR[B_IT], blR[B_IT];

  auto loadRegs = [&](int kt) {
    const int k0 = kt * BK;
#pragma unroll
    for (int it = 0; it < A_IT; ++it) {
      const size_t base = (size_t)(rowBase + it * 32 + srA) * K + k0 + sg_ * 8;
      ahR[it] = *reinterpret_cast<const uint4*>(Ahi + base);
      alR[it] = *reinterpret_cast<const uint4*>(Alo + base);
    }
#pragma unroll
    for (int it = 0; it < B_IT; ++it) {
      const size_t base = (size_t)(colBase + it * 32 + srA) * K + k0 + sg_ * 8;
      bhR[it] = *reinterpret_cast<const uint4*>(Bhi + base);
      blR[it] = *reinterpret_cast<const uint4*>(Blo + base);
    }
  };

  auto writeLDS = [&](int buf) {
#pragma unroll
    for (int it = 0; it < A_IT; ++it) {
      const int off = ((it * 32 + srA) << 6) + (swg << 3);
      *reinterpret_cast<uint4*>(&AsH[buf][off]) = ahR[it];
      *reinterpret_cast<uint4*>(&AsL[buf][off]) = alR[it];
    }
#pragma unroll
    for (int it = 0; it < B_IT; ++it) {
      const int off = ((it * 32 + srA) << 6) + (swg << 3);
      *reinterpret_cast<uint4*>(&BsH[buf][off]) = bhR[it];
      *reinterpret_cast<uint4*>(&BsL[buf][off]) = blR[it];
    }
  };

  // prologue: tile0 -> LDS buf0; tile1 -> regs
  loadRegs(0);
  writeLDS(0);
  if (nt > 1) loadRegs(1);

  for (int t = 0; t < nt; ++t) {
    __syncthreads();
    const int cur = t & 1;
    if (t + 1 < nt) writeLDS(cur ^ 1);
    if (t + 2 < nt) loadRegs(t + 2);

#pragma unroll
    for (int ks = 0; ks < 2; ++ks) {
      short8v ah[MI], al[MI], bh[NI], bl[NI];
#pragma unroll
      for (int mi = 0; mi < MI; ++mi) {
        const int r = wr * WT_M + mi * 16 + l15;
        const int off = (r << 6) + (((ks * 4 + l4) ^ (r & 7)) << 3);
        ah[mi] = *reinterpret_cast<const short8v*>(&AsH[cur][off]);
        al[mi] = *reinterpret_cast<const short8v*>(&AsL[cur][off]);
      }
#pragma unroll
      for (int ni = 0; ni < NI; ++ni) {
        const int r = wc * WT_N + ni * 16 + l15;
        const int off = (r << 6) + (((ks * 4 + l4) ^ (r & 7)) << 3);
        bh[ni] = *reinterpret_cast<const short8v*>(&BsH[cur][off]);
        bl[ni] = *reinterpret_cast<const short8v*>(&BsL[cur][off]);
      }
#pragma unroll
      for (int mi = 0; mi < MI; ++mi)
#pragma unroll
        for (int ni = 0; ni < NI; ++ni) {
          acc[mi][ni] = __builtin_amdgcn_mfma_f32_16x16x32_bf16(ah[mi], bh[ni], acc[mi][ni], 0, 0, 0);
          acc[mi][ni] = __builtin_amdgcn_mfma_f32_16x16x32_bf16(al[mi], bh[ni], acc[mi][ni], 0, 0, 0);
          acc[mi][ni] = __builtin_amdgcn_mfma_f32_16x16x32_bf16(ah[mi], bl[ni], acc[mi][ni], 0, 0, 0);
        }
    }
  }

#pragma unroll
  for (int mi = 0; mi < MI; ++mi) {
#pragma unroll
    for (int ni = 0; ni < NI; ++ni) {
      const int col = colBase + wc * WT_N + ni * 16 + l15;
      const float bv = bias[col];
#pragma unroll
      for (int j = 0; j < 4; ++j) {
        const int row = rowBase + wr * WT_M + mi * 16 + l4 * 4 + j;
        float v = acc[mi][ni][j] + bv;
        if (RELU) v = fmaxf(v, 0.f);
        if (SPLIT_OUT) {
          unsigned short h, l;
          split_bf16(v, h, l);
          Chi[(size_t)row * N + col] = h;
          Clo[(size_t)row * N + col] = l;
        } else {
          C[(size_t)row * N + col] = v;
        }
      }
    }
  }
}

// ---------------------------------------------------------------------------
// K transpose: qkvb k-slice -> ktb[bh][d][kk]  (fp32)
// ---------------------------------------------------------------------------
__global__ __launch_bounds__(256) void txp_kernel(
    const float* __restrict__ qkvb, float* __restrict__ ktb) {
  __shared__ float tile[32][33];
  const int bh = blockIdx.z;
  const int b = bh >> 3, h = bh & 7;
  const int kk0 = blockIdx.x * 32, d0 = blockIdx.y * 32;
  const int tx = threadIdx.x & 31, ty = threadIdx.x >> 5;
#pragma unroll
  for (int i = 0; i < 4; ++i) {
    const int kk = kk0 + ty + i * 8;
    tile[ty + i * 8][tx] = qkvb[(size_t)(b * LL + kk) * QKVN + DM + h * DHD + d0 + tx];
  }
  __syncthreads();
#pragma unroll
  for (int i = 0; i < 4; ++i) {
    const int d = d0 + ty + i * 8;
    ktb[((size_t)bh * DHD + d) * LL + kk0 + tx] = tile[tx][ty + i * 8];
  }
}

// ---------------------------------------------------------------------------
// Fused attention (vector fp32): TQ=8 q rows per block, transposed LDS.
// ---------------------------------------------------------------------------
constexpr int TQ = 8;

__global__ __launch_bounds__(256) void attn_kernel(
    const float* __restrict__ qkvb, const float* __restrict__ ktb,
    const float* __restrict__ kernS,
    unsigned short* __restrict__ ctxhi, unsigned short* __restrict__ ctxlo) {
  const int qt = blockIdx.x;
  const int h = blockIdx.y;
  const int b = blockIdx.z;
  const int tid = threadIdx.x;
  const int q0 = qt * TQ;

  __shared__ float qst[DHD][TQ];
  __shared__ float lst[LL][TQ];
  __shared__ float red[4][TQ][DHD];
  __shared__ float invS[TQ];

  {
    const int d = tid & 63;
    const int qq0 = tid >> 6;
#pragma unroll
    for (int rep = 0; rep < 2; ++rep) {
      const int qq = qq0 + rep * 4;
      qst[d][qq] = qkvb[(size_t)(b * LL + q0 + qq) * QKVN + h * DHD + d];
    }
  }
  __syncthreads();

  {
    const int kk = tid;
    const float* kcol = ktb + (size_t)(b * NH + h) * DHD * LL;
    float dot0[TQ] = {}, dot1[TQ] = {};
#pragma unroll 4
    for (int d = 0; d < DHD; ++d) {
      const float ka = kcol[(size_t)d * LL + kk];
      const float kb2 = kcol[(size_t)d * LL + kk + 256];
      const float4 qa = *reinterpret_cast<const float4*>(&qst[d][0]);
      const float4 qb2 = *reinterpret_cast<const float4*>(&qst[d][4]);
      dot0[0] += qa.x * ka; dot0[1] += qa.y * ka; dot0[2] += qa.z * ka; dot0[3] += qa.w * ka;
      dot0[4] += qb2.x * ka; dot0[5] += qb2.y * ka; dot0[6] += qb2.z * ka; dot0[7] += qb2.w * ka;
      dot1[0] += qa.x * kb2; dot1[1] += qa.y * kb2; dot1[2] += qa.z * kb2; dot1[3] += qa.w * kb2;
      dot1[4] += qb2.x * kb2; dot1[5] += qb2.y * kb2; dot1[6] += qb2.z * kb2; dot1[7] += qb2.w * kb2;
    }
#pragma unroll
    for (int qq = 0; qq < TQ; ++qq) {
      const size_t kbase = ((size_t)b * LL + q0 + qq) * LL;
      lst[kk][qq] = dot0[qq] * 0.125f + kernS[kbase + kk];
      lst[kk + 256][qq] = dot1[qq] * 0.125f + kernS[kbase + kk + 256];
    }
  }
  __syncthreads();

  {
    const int row = tid >> 5;
    const int l32 = tid & 31;
    float m = -1e30f;
#pragma unroll
    for (int j = 0; j < 16; ++j) m = fmaxf(m, lst[l32 + j * 32][row]);
#pragma unroll
    for (int s = 16; s; s >>= 1) m = fmaxf(m, __shfl_xor(m, s, 32));
    float sum = 0.f;
#pragma unroll
    for (int j = 0; j < 16; ++j) {
      const float e = __expf(lst[l32 + j * 32][row] - m);
      lst[l32 + j * 32][row] = e;
      sum += e;
    }
#pragma unroll
    for (int s = 16; s; s >>= 1) sum += __shfl_xor(sum, s, 32);
    if (l32 == 0) invS[row] = 1.0f / sum;
  }
  __syncthreads();

  const int d = tid & 63;
  const int c = tid >> 6;
  float acc[TQ] = {};
  for (int kk = c * 128; kk < c * 128 + 128; ++kk) {
    const float vv = qkvb[(size_t)(b * LL + kk) * QKVN + 2 * DM + h * DHD + d];
    const float4 pa = *reinterpret_cast<const float4*>(&lst[kk][0]);
    const float4 pb2 = *reinterpret_cast<const float4*>(&lst[kk][4]);
    acc[0] += pa.x * vv; acc[1] += pa.y * vv; acc[2] += pa.z * vv; acc[3] += pa.w * vv;
    acc[4] += pb2.x * vv; acc[5] += pb2.y * vv; acc[6] += pb2.z * vv; acc[7] += pb2.w * vv;
  }
#pragma unroll
  for (int qq = 0; qq < TQ; ++qq) red[c][qq][d] = acc[qq];
  __syncthreads();
  if (c == 0) {
#pragma unroll
    for (int qq = 0; qq < TQ; ++qq) {
      const float r = ((red[0][qq][d] + red[1][qq][d]) + (red[2][qq][d] + red[3][qq][d])) * invS[qq];
      unsigned short hh, ll;
      split_bf16(r, hh, ll);
      const size_t o = (size_t)(b * LL + q0 + qq) * DM + h * DHD + d;
      ctxhi[o] = hh;
      ctxlo[o] = ll;
    }
  }
}

// ---------------------------------------------------------------------------
// Fused residual + LayerNorm; writes fp32 + bf16 hi/lo decomposition.
// ---------------------------------------------------------------------------
__global__ __launch_bounds__(256) void resid_ln_kernel(
    const float* __restrict__ X, const float* __restrict__ R,
    const float* __restrict__ g, const float* __restrict__ bta,
    float* __restrict__ Out, unsigned short* __restrict__ OutHi,
    unsigned short* __restrict__ OutLo) {
  const int row = blockIdx.x * 4 + (threadIdx.x >> 6);
  const int lane = threadIdx.x & 63;
  const float* x = X + (size_t)row * DM;
  const float* r = R + (size_t)row * DM;

  float v[8];
  float s = 0.f;
#pragma unroll
  for (int j = 0; j < 2; ++j) {
    const float4 a = *reinterpret_cast<const float4*>(x + lane * 8 + j * 4);
    const float4 c = *reinterpret_cast<const float4*>(r + lane * 8 + j * 4);
    v[j * 4 + 0] = a.x + c.x;
    v[j * 4 + 1] = a.y + c.y;
    v[j * 4 + 2] = a.z + c.z;
    v[j * 4 + 3] = a.w + c.w;
    s += v[j * 4 + 0] + v[j * 4 + 1] + v[j * 4 + 2] + v[j * 4 + 3];
  }
#pragma unroll
  for (int m = 1; m < 64; m <<= 1) s += __shfl_xor(s, m, 64);
  const float mean = s * (1.f / DM);
  float var = 0.f;
#pragma unroll
  for (int j = 0; j < 8; ++j) {
    const float dlt = v[j] - mean;
    var += dlt * dlt;
  }
#pragma unroll
  for (int m = 1; m < 64; m <<= 1) var += __shfl_xor(var, m, 64);
  var *= (1.f / DM);
  const float inv = 1.0f / sqrtf(var + 1e-6f);

  unsigned short hs[8], ls[8];
#pragma unroll
  for (int j = 0; j < 2; ++j) {
    const float4 gg = *reinterpret_cast<const float4*>(g + lane * 8 + j * 4);
    const float4 bb = *reinterpret_cast<const float4*>(bta + lane * 8 + j * 4);
    float4 o;
    o.x = (v[j * 4 + 0] - mean) * inv * gg.x + bb.x;
    o.y = (v[j * 4 + 1] - mean) * inv * gg.y + bb.y;
    o.z = (v[j * 4 + 2] - mean) * inv * gg.z + bb.z;
    o.w = (v[j * 4 + 3] - mean) * inv * gg.w + bb.w;
    *reinterpret_cast<float4*>(Out + (size_t)row * DM + lane * 8 + j * 4) = o;
    split_bf16(o.x, hs[j * 4 + 0], ls[j * 4 + 0]);
    split_bf16(o.y, hs[j * 4 + 1], ls[j * 4 + 1]);
    split_bf16(o.z, hs[j * 4 + 2], ls[j * 4 + 2]);
    split_bf16(o.w, hs[j * 4 + 3], ls[j * 4 + 3]);
  }
  uint4 hv, lv;
  hv.x = (unsigned)hs[0] | ((unsigned)hs[1] << 16);
  hv.y = (unsigned)hs[2] | ((unsigned)hs[3] << 16);
  hv.z = (unsigned)hs[4] | ((unsigned)hs[5] << 16);
  hv.w = (unsigned)hs[6] | ((unsigned)hs[7] << 16);
  lv.x = (unsigned)ls[0] | ((unsigned)ls[1] << 16);
  lv.y = (unsigned)ls[2] | ((unsigned)ls[3] << 16);
  lv.z = (unsigned)ls[4] | ((unsigned)ls[5] << 16);
  lv.w = (unsigned)ls[6] | ((unsigned)ls[7] << 16);
  *reinterpret_cast<uint4*>(OutHi + (size_t)row * DM + lane * 8) = hv;
  *reinterpret_cast<uint4*>(OutLo + (size_t)row * DM + lane * 8) = lv;
}

// ---------------------------------------------------------------------------
// launch
// ---------------------------------------------------------------------------
extern "C" void kernel_launch(void* const* d_in, const int* in_sizes, int n_in,
                              void* d_out, int out_size, void* d_ws, size_t ws_size,
                              hipStream_t stream) {
  const float* x_in = (const float*)d_in[0];
  const float* t = (const float*)d_in[1];
  const float* wq = (const float*)d_in[2];
  const float* bq = (const float*)d_in[3];
  const float* wk = (const float*)d_in[4];
  const float* bk = (const float*)d_in[5];
  const float* wv = (const float*)d_in[6];
  const float* bv = (const float*)d_in[7];
  const float* wo = (const float*)d_in[8];
  const float* bo = (const float*)d_in[9];
  const float* w1 = (const float*)d_in[10];
  const float* b1 = (const float*)d_in[11];
  const float* w2 = (const float*)d_in[12];
  const float* b2 = (const float*)d_in[13];
  const float* ln1g = (const float*)d_in[14];
  const float* ln1b = (const float*)d_in[15];
  const float* ln2g = (const float*)d_in[16];
  const float* ln2b = (const float*)d_in[17];
  const float* pw1 = (const float*)d_in[18];
  const float* pb1 = (const float*)d_in[19];
  const float* pw2 = (const float*)d_in[20];
  const float* pb2 = (const float*)d_in[21];
  const float* sw1 = (const float*)d_in[22];
  const float* sb1 = (const float*)d_in[23];
  const float* sw2 = (const float*)d_in[24];
  const float* sb2 = (const float*)d_in[25];
  const float* bw1 = (const float*)d_in[26];
  const float* bb1 = (const float*)d_in[27];
  const float* bw2 = (const float*)d_in[28];
  const float* bb2 = (const float*)d_in[29];

  char* wsb = (char*)d_ws;
  size_t off = 0;
  auto allocB = [&](size_t bytes) {
    char* p = wsb + off;
    off += (bytes + 255) & ~(size_t)255;
    return p;
  };
  float* tpb = (float*)allocB(ROWS * TD * 4);
  float* sgb = (float*)allocB(ROWS * TD * 4);
  float* beb = (float*)allocB(ROWS * TD * 4);
  float* kernS = (float*)allocB((size_t)BB * LL * LL * 4);
  float* qkvb = (float*)allocB((size_t)ROWS * QKVN * 4);        // } h hi/lo aliases
  float* ktb = (float*)allocB((size_t)BB * NH * DHD * LL * 4);  // } this region
  float* ao = (float*)allocB((size_t)ROWS * DM * 4);
  float* xb = (float*)allocB((size_t)ROWS * DM * 4);
  float* fb = (float*)allocB((size_t)ROWS * DM * 4);
  float* xn = (float*)allocB((size_t)ROWS * DM * 4);
  float* qkvbias = (float*)allocB(QKVN * 4);
  unsigned short* qkvwt_hi = (unsigned short*)allocB((size_t)QKVN * DM * 2);
  unsigned short* qkvwt_lo = (unsigned short*)allocB((size_t)QKVN * DM * 2);
  unsigned short* wot_hi = (unsigned short*)allocB((size_t)DM * DM * 2);
  unsigned short* wot_lo = (unsigned short*)allocB((size_t)DM * DM * 2);
  unsigned short* w1t_hi = (unsigned short*)allocB((size_t)FF * DM * 2);
  unsigned short* w1t_lo = (unsigned short*)allocB((size_t)FF * DM * 2);
  unsigned short* w2t_hi = (unsigned short*)allocB((size_t)DM * FF * 2);
  unsigned short* w2t_lo = (unsigned short*)allocB((size_t)DM * FF * 2);
  unsigned short* xhi = (unsigned short*)allocB((size_t)ROWS * DM * 2);
  unsigned short* xlo = (unsigned short*)allocB((size_t)ROWS * DM * 2);
  unsigned short* ctxhi = (unsigned short*)allocB((size_t)ROWS * DM * 2);
  unsigned short* ctxlo = (unsigned short*)allocB((size_t)ROWS * DM * 2);
  // h hi/lo alias over [qkvb, ktb] (both dead by FFN1 time)
  unsigned short* hhi = (unsigned short*)qkvb;
  unsigned short* hlo = hhi + (size_t)ROWS * FF;

  const float* xcur = x_in;

  for (int i = 0; i < NLAYERS; ++i) {
    td_kernel<<<dim3(16, 16), 256, 0, stream>>>(wq + (size_t)i * DM * DM, qkvwt_hi, qkvwt_lo, DM, DM);
    td_kernel<<<dim3(16, 16), 256, 0, stream>>>(wk + (size_t)i * DM * DM, qkvwt_hi + (size_t)DM * DM, qkvwt_lo + (size_t)DM * DM, DM, DM);
    td_kernel<<<dim3(16, 16), 256, 0, stream>>>(wv + (size_t)i * DM * DM, qkvwt_hi + (size_t)2 * DM * DM, qkvwt_lo + (size_t)2 * DM * DM, DM, DM);
    td_kernel<<<dim3(16, 16), 256, 0, stream>>>(wo + (size_t)i * DM * DM, wot_hi, wot_lo, DM, DM);
    td_kernel<<<dim3(16, 64), 256, 0, stream>>>(w1 + (size_t)i * DM * FF, w1t_hi, w1t_lo, DM, FF);
    td_kernel<<<dim3(64, 16), 256, 0, stream>>>(w2 + (size_t)i * FF * DM, w2t_hi, w2t_lo, FF, DM);
    qkvbias_kernel<<<(QKVN + 255) / 256, 256, 0, stream>>>(bq + i * DM, bk + i * DM, bv + i * DM, qkvbias);

    small_ffn_kernel<<<ROWS / 256, 256, 0, stream>>>(
        t, pw1 + i * TD, pb1 + i * TD, pw2 + i * TD * TD, pb2 + i * TD,
        sw1 + i * TD, sb1 + i * TD, sw2 + i * TD * TD, sb2 + i * TD,
        bw1 + i * TD, bb1 + i * TD, bw2 + i * TD * TD, bb2 + i * TD,
        tpb, sgb, beb);
    kern_kernel<<<dim3(LL / 256, LL, BB), 256, 0, stream>>>(t, tpb, sgb, beb, kernS);

    if (i == 0) {
      decomp_kernel<<<(ROWS * DM / 4 + 255) / 256, 256, 0, stream>>>(x_in, xhi, xlo, ROWS * DM / 4);
    }

    // QKV fused GEMM: [4096][1536], grid 12x32 = 384 blocks
    gemm_mfma<128, false, false><<<dim3(QKVN / 128, ROWS / 128), 256, 0, stream>>>(
        xhi, xlo, qkvwt_hi, qkvwt_lo, qkvbias, qkvb, nullptr, nullptr, ROWS, QKVN, DM);

    txp_kernel<<<dim3(LL / 32, DHD / 32, BB * NH), 256, 0, stream>>>(qkvb, ktb);

    attn_kernel<<<dim3(LL / TQ, NH, BB), 256, 0, stream>>>(qkvb, ktb, kernS, ctxhi, ctxlo);

    // O projection: grid 8x32 = 256 blocks
    gemm_mfma<64, false, false><<<dim3(DM / 64, ROWS / 128), 256, 0, stream>>>(
        ctxhi, ctxlo, wot_hi, wot_lo, bo + i * DM, ao, nullptr, nullptr, ROWS, DM, DM);

    resid_ln_kernel<<<ROWS / 4, 256, 0, stream>>>(
        xcur, ao, ln1g + i * DM, ln1b + i * DM, xb, xhi, xlo);

    // FFN1 (relu, split bf16 out): grid 16x32 = 512 blocks
    gemm_mfma<128, true, true><<<dim3(FF / 128, ROWS / 128), 256, 0, stream>>>(
        xhi, xlo, w1t_hi, w1t_lo, b1 + i * FF, nullptr, hhi, hlo, ROWS, FF, DM);

    // FFN2: grid 8x32 = 256 blocks, K=2048
    gemm_mfma<64, false, false><<<dim3(DM / 64, ROWS / 128), 256, 0, stream>>>(
        hhi, hlo, w2t_hi, w2t_lo, b2 + i * DM, fb, nullptr, nullptr, ROWS, DM, FF);

    float* ln2_out = (i == NLAYERS - 1) ? (float*)d_out : xn;
    resid_ln_kernel<<<ROWS / 4, 256, 0, stream>>>(
        xb, fb, ln2g + i * DM, ln2b + i * DM, ln2_out, xhi, xlo);

    xcur = xn;
  }
}